// Round 1
// baseline (805.673 us; speedup 1.0000x reference)
//
#include <hip/hip_runtime.h>
#include <hip/hip_bf16.h>

// GraphSAGE 2-layer forward on MI355X.
// Sizes fixed by the reference: N=100000 nodes, E=1.6M edges, C: 32 -> 64 -> 32.
//
// ws layout (floats):
//   agg1 : N*32   (zeroed)
//   agg2 : N*64   (zeroed)
//   cnt  : N      (zeroed)
//   h    : N*64   (fully overwritten, no zero needed)
// total = N*161 floats = 64.4 MB

#define N_IN_C  32
#define N_HID_C 64
#define N_OUT_C 32

// ---- layer-1 aggregation: agg1[dst] += x[src] (32ch), cnt[dst] += 1 ----
__global__ void agg1_kernel(const float* __restrict__ x,
                            const int* __restrict__ src,
                            const int* __restrict__ dst,
                            float* __restrict__ agg,
                            float* __restrict__ cnt, int E) {
    int t = blockIdx.x * blockDim.x + threadIdx.x;
    int e = t >> 5;          // 32 lanes per edge
    int c = t & 31;
    if (e >= E) return;
    int s = src[e];
    int d = dst[e];
    atomicAdd(&agg[d * N_IN_C + c], x[s * N_IN_C + c]);
    if (c == 0) atomicAdd(&cnt[d], 1.0f);
}

// ---- dense layer 1: h = relu(agg1/cnt @ W1_l + b1 + x @ W1_r) ----
__global__ void dense1_kernel(const float* __restrict__ x,
                              const float* __restrict__ agg,
                              const float* __restrict__ cnt,
                              const float* __restrict__ W1l,   // [32][64]
                              const float* __restrict__ b1,    // [64]
                              const float* __restrict__ W1r,   // [32][64]
                              float* __restrict__ h, int N) {
    __shared__ float sWl[N_IN_C * N_HID_C];
    __shared__ float sWr[N_IN_C * N_HID_C];
    __shared__ float sb[N_HID_C];
    for (int i = threadIdx.x; i < N_IN_C * N_HID_C; i += blockDim.x) {
        sWl[i] = W1l[i];
        sWr[i] = W1r[i];
    }
    if (threadIdx.x < N_HID_C) sb[threadIdx.x] = b1[threadIdx.x];
    __syncthreads();

    int t = blockIdx.x * blockDim.x + threadIdx.x;
    int n = t >> 6;          // one wave (64 lanes) per node, lane = out channel
    int oc = t & 63;
    if (n >= N) return;

    float inv = 1.0f / fmaxf(cnt[n], 1.0f);
    const float* xr = x + n * N_IN_C;
    const float* ar = agg + n * N_IN_C;
    float acc = sb[oc];
#pragma unroll
    for (int k = 0; k < N_IN_C; ++k) {
        acc += ar[k] * inv * sWl[k * N_HID_C + oc] + xr[k] * sWr[k * N_HID_C + oc];
    }
    h[n * N_HID_C + oc] = fmaxf(acc, 0.0f);
}

// ---- layer-2 aggregation: agg2[dst] += h[src] (64ch) ----
__global__ void agg2_kernel(const float* __restrict__ h,
                            const int* __restrict__ src,
                            const int* __restrict__ dst,
                            float* __restrict__ agg, int E) {
    int t = blockIdx.x * blockDim.x + threadIdx.x;
    int e = t >> 6;          // 64 lanes (full wave) per edge
    int c = t & 63;
    if (e >= E) return;
    atomicAdd(&agg[dst[e] * N_HID_C + c], h[src[e] * N_HID_C + c]);
}

// ---- dense layer 2: out = agg2/cnt @ W2_l + b2 + h @ W2_r  (no relu) ----
__global__ void dense2_kernel(const float* __restrict__ h,
                              const float* __restrict__ agg,
                              const float* __restrict__ cnt,
                              const float* __restrict__ W2l,   // [64][32]
                              const float* __restrict__ b2,    // [32]
                              const float* __restrict__ W2r,   // [64][32]
                              float* __restrict__ out, int N) {
    __shared__ float sWl[N_HID_C * N_OUT_C];
    __shared__ float sWr[N_HID_C * N_OUT_C];
    __shared__ float sb[N_OUT_C];
    for (int i = threadIdx.x; i < N_HID_C * N_OUT_C; i += blockDim.x) {
        sWl[i] = W2l[i];
        sWr[i] = W2r[i];
    }
    if (threadIdx.x < N_OUT_C) sb[threadIdx.x] = b2[threadIdx.x];
    __syncthreads();

    int t = blockIdx.x * blockDim.x + threadIdx.x;
    int n = t >> 5;          // 32 lanes per node, lane = out channel
    int oc = t & 31;
    if (n >= N) return;

    float inv = 1.0f / fmaxf(cnt[n], 1.0f);
    const float* hr = h + n * N_HID_C;
    const float* ar = agg + n * N_HID_C;
    float acc = sb[oc];
#pragma unroll
    for (int k = 0; k < N_HID_C; ++k) {
        acc += ar[k] * inv * sWl[k * N_OUT_C + oc] + hr[k] * sWr[k * N_OUT_C + oc];
    }
    out[n * N_OUT_C + oc] = acc;
}

extern "C" void kernel_launch(void* const* d_in, const int* in_sizes, int n_in,
                              void* d_out, int out_size, void* d_ws, size_t ws_size,
                              hipStream_t stream) {
    const float* x   = (const float*)d_in[0];
    const int*   ei  = (const int*)d_in[1];   // [2][E] int32
    const float* W1l = (const float*)d_in[2];
    const float* b1  = (const float*)d_in[3];
    const float* W1r = (const float*)d_in[4];
    const float* W2l = (const float*)d_in[5];
    const float* b2  = (const float*)d_in[6];
    const float* W2r = (const float*)d_in[7];
    float* out = (float*)d_out;

    const int N = in_sizes[0] / N_IN_C;       // 100000
    const int E = in_sizes[1] / 2;            // 1600000
    const int* src = ei;
    const int* dst = ei + E;

    float* ws   = (float*)d_ws;
    float* agg1 = ws;                          // N*32
    float* agg2 = ws + (size_t)N * 32;         // N*64
    float* cnt  = ws + (size_t)N * 96;         // N
    float* h    = ws + (size_t)N * 97;         // N*64

    // zero agg1 + agg2 + cnt (contiguous N*97 floats)
    hipMemsetAsync(d_ws, 0, (size_t)N * 97 * sizeof(float), stream);

    {   // layer-1 aggregation: 32 threads per edge
        long long threads = (long long)E * 32;
        int blk = 256;
        long long grid = (threads + blk - 1) / blk;
        agg1_kernel<<<(int)grid, blk, 0, stream>>>(x, src, dst, agg1, cnt, E);
    }
    {   // dense layer 1: 64 threads per node
        long long threads = (long long)N * 64;
        int blk = 256;
        long long grid = (threads + blk - 1) / blk;
        dense1_kernel<<<(int)grid, blk, 0, stream>>>(x, agg1, cnt, W1l, b1, W1r, h, N);
    }
    {   // layer-2 aggregation: 64 threads per edge
        long long threads = (long long)E * 64;
        int blk = 256;
        long long grid = (threads + blk - 1) / blk;
        agg2_kernel<<<(int)grid, blk, 0, stream>>>(h, src, dst, agg2, E);
    }
    {   // dense layer 2: 32 threads per node
        long long threads = (long long)N * 32;
        int blk = 256;
        long long grid = (threads + blk - 1) / blk;
        dense2_kernel<<<(int)grid, blk, 0, stream>>>(h, agg2, cnt, W2l, b2, W2r, out, N);
    }
}

// Round 2
// 553.465 us; speedup vs baseline: 1.4557x; 1.4557x over previous
//
#include <hip/hip_runtime.h>
#include <hip/hip_bf16.h>

// GraphSAGE 2-layer forward, CSR-gather formulation (no float atomics).
// N=100000 nodes, E=1.6M edges, C: 32 -> 64 -> 32.
//
// Pipeline (all on `stream`, graph-capture safe):
//   memset cnt_i (N ints)
//   hist:   cnt_i[dst[e]]++                       (int atomics)
//   scan1/2/3: exclusive prefix sum -> row_start[N+1], cursor[N]
//   fill:   sorted_src[atomicInc(cursor[dst])] = src   (CSR by dst)
//   layer1: per-node gather x[src] (32ch) -> dense1 -> h (N*64), hW = h@W2_l (N*32)
//   layer2: per-node gather hW[src] (32ch) -> + h@W2_r + b2 -> out

#define SCAN_BLK   256
#define SCAN_ITEMS 4
#define SCAN_CHUNK (SCAN_BLK * SCAN_ITEMS)   // 1024

__global__ void hist_kernel(const int* __restrict__ dst, int* __restrict__ cnt, int E) {
    int e = blockIdx.x * blockDim.x + threadIdx.x;
    if (e < E) atomicAdd(&cnt[dst[e]], 1);
}

// block partial sums over padded domain [0, n] (element n reads 0)
__global__ void scan1_kernel(const int* __restrict__ cnt, int* __restrict__ bsum, int n) {
    __shared__ int red[SCAN_BLK];
    int base = blockIdx.x * SCAN_CHUNK + threadIdx.x * SCAN_ITEMS;
    int s = 0;
#pragma unroll
    for (int j = 0; j < SCAN_ITEMS; ++j) {
        int i = base + j;
        s += (i < n) ? cnt[i] : 0;
    }
    red[threadIdx.x] = s;
    __syncthreads();
    for (int off = SCAN_BLK / 2; off > 0; off >>= 1) {
        if (threadIdx.x < off) red[threadIdx.x] += red[threadIdx.x + off];
        __syncthreads();
    }
    if (threadIdx.x == 0) bsum[blockIdx.x] = red[0];
}

// single-block exclusive scan of nb (<=256) block sums
__global__ void scan2_kernel(int* __restrict__ bsum, int nb) {
    __shared__ int buf[SCAN_BLK];
    int t = threadIdx.x;
    int v = (t < nb) ? bsum[t] : 0;
    buf[t] = v;
    __syncthreads();
    for (int off = 1; off < SCAN_BLK; off <<= 1) {
        int add = (t >= off) ? buf[t - off] : 0;
        __syncthreads();
        buf[t] += add;
        __syncthreads();
    }
    if (t < nb) bsum[t] = buf[t] - v;   // exclusive
}

// per-element exclusive scan + block offset -> row_start[0..n], cursor[0..n-1]
__global__ void scan3_kernel(const int* __restrict__ cnt, const int* __restrict__ bsum,
                             int* __restrict__ row_start, int* __restrict__ cursor, int n) {
    __shared__ int tsum[SCAN_BLK];
    int t = threadIdx.x;
    int base = blockIdx.x * SCAN_CHUNK + t * SCAN_ITEMS;
    int v[SCAN_ITEMS];
#pragma unroll
    for (int j = 0; j < SCAN_ITEMS; ++j) {
        int i = base + j;
        v[j] = (i < n) ? cnt[i] : 0;
    }
    int mine = v[0] + v[1] + v[2] + v[3];
    tsum[t] = mine;
    __syncthreads();
    for (int off = 1; off < SCAN_BLK; off <<= 1) {
        int add = (t >= off) ? tsum[t - off] : 0;
        __syncthreads();
        tsum[t] += add;
        __syncthreads();
    }
    int run = tsum[t] - mine + bsum[blockIdx.x];
#pragma unroll
    for (int j = 0; j < SCAN_ITEMS; ++j) {
        int i = base + j;
        if (i <= n) {
            row_start[i] = run;
            if (i < n) cursor[i] = run;
        }
        run += v[j];
    }
}

__global__ void fill_kernel(const int* __restrict__ src, const int* __restrict__ dst,
                            int* __restrict__ cursor, int* __restrict__ sorted_src, int E) {
    int e = blockIdx.x * blockDim.x + threadIdx.x;
    if (e < E) {
        int pos = atomicAdd(&cursor[dst[e]], 1);
        sorted_src[pos] = src[e];
    }
}

// one wave per node: gather-mean x[src] (32ch) -> h = relu(agg@W1l + b1 + x@W1r)
// then hW = h@W2l (pre-transform for layer-2 aggregation, 32ch)
__global__ __launch_bounds__(256) void layer1_kernel(
        const float* __restrict__ x, const int* __restrict__ row_start,
        const int* __restrict__ sorted_src,
        const float* __restrict__ W1l, const float* __restrict__ b1,
        const float* __restrict__ W1r, const float* __restrict__ W2l,
        float* __restrict__ h, float* __restrict__ hW, int N) {
    __shared__ float sW1l[32 * 64];
    __shared__ float sW1r[32 * 64];
    __shared__ float sW2l[64 * 32];
    __shared__ float sb1[64];
    __shared__ float sAgg[4][32];
    __shared__ float sX[4][32];
    __shared__ float sH[4][64];
    for (int i = threadIdx.x; i < 2048; i += 256) {
        sW1l[i] = W1l[i];
        sW1r[i] = W1r[i];
        sW2l[i] = W2l[i];
    }
    if (threadIdx.x < 64) sb1[threadIdx.x] = b1[threadIdx.x];
    __syncthreads();

    int w = threadIdx.x >> 6;
    int lane = threadIdx.x & 63;
    int n = blockIdx.x * 4 + w;
    bool active = n < N;

    int rs = 0, re = 0;
    float inv = 1.0f;
    if (active) {
        rs = row_start[n];
        re = row_start[n + 1];
        inv = 1.0f / fmaxf((float)(re - rs), 1.0f);
    }
    int c = lane & 31, half = lane >> 5;
    float a = 0.0f;
    if (active) {
        for (int i = rs + half; i < re; i += 2)
            a += x[(size_t)sorted_src[i] * 32 + c];
    }
    a += __shfl_xor(a, 32);     // combine the two edge-parallel halves
    if (active && lane < 32) {
        sAgg[w][lane] = a * inv;
        sX[w][lane] = x[(size_t)n * 32 + lane];
    }
    __syncthreads();

    float acc = sb1[lane];
    if (active) {
#pragma unroll
        for (int k = 0; k < 32; ++k)
            acc += sAgg[w][k] * sW1l[k * 64 + lane] + sX[w][k] * sW1r[k * 64 + lane];
    }
    float hv = fmaxf(acc, 0.0f);
    if (active) {
        h[(size_t)n * 64 + lane] = hv;
        sH[w][lane] = hv;
    }
    __syncthreads();

    if (active && lane < 32) {
        float a2 = 0.0f;
#pragma unroll
        for (int k = 0; k < 64; ++k) a2 += sH[w][k] * sW2l[k * 32 + lane];
        hW[(size_t)n * 32 + lane] = a2;
    }
}

// one wave per node: gather-mean hW[src] (32ch, already @W2l) + h@W2r + b2 -> out
__global__ __launch_bounds__(256) void layer2_kernel(
        const float* __restrict__ h, const float* __restrict__ hW,
        const int* __restrict__ row_start, const int* __restrict__ sorted_src,
        const float* __restrict__ W2r, const float* __restrict__ b2,
        float* __restrict__ out, int N) {
    __shared__ float sW2r[64 * 32];
    __shared__ float sb2[32];
    __shared__ float sH[4][64];
    for (int i = threadIdx.x; i < 2048; i += 256) sW2r[i] = W2r[i];
    if (threadIdx.x < 32) sb2[threadIdx.x] = b2[threadIdx.x];
    __syncthreads();

    int w = threadIdx.x >> 6;
    int lane = threadIdx.x & 63;
    int n = blockIdx.x * 4 + w;
    bool active = n < N;

    int rs = 0, re = 0;
    float inv = 1.0f;
    if (active) {
        rs = row_start[n];
        re = row_start[n + 1];
        inv = 1.0f / fmaxf((float)(re - rs), 1.0f);
    }
    int c = lane & 31, half = lane >> 5;
    float a = 0.0f;
    if (active) {
        for (int i = rs + half; i < re; i += 2)
            a += hW[(size_t)sorted_src[i] * 32 + c];
    }
    a += __shfl_xor(a, 32);
    if (active) sH[w][lane] = h[(size_t)n * 64 + lane];
    __syncthreads();

    if (active) {
        float p = 0.0f;
#pragma unroll
        for (int kk = 0; kk < 32; ++kk) {
            int k = half * 32 + kk;
            p += sH[w][k] * sW2r[k * 32 + c];
        }
        p += __shfl_xor(p, 32);  // combine k-halves
        if (lane < 32) out[(size_t)n * 32 + c] = a * inv + sb2[c] + p;
    }
}

extern "C" void kernel_launch(void* const* d_in, const int* in_sizes, int n_in,
                              void* d_out, int out_size, void* d_ws, size_t ws_size,
                              hipStream_t stream) {
    const float* x   = (const float*)d_in[0];
    const int*   ei  = (const int*)d_in[1];
    const float* W1l = (const float*)d_in[2];
    const float* b1  = (const float*)d_in[3];
    const float* W1r = (const float*)d_in[4];
    const float* W2l = (const float*)d_in[5];
    const float* b2  = (const float*)d_in[6];
    const float* W2r = (const float*)d_in[7];
    float* out = (float*)d_out;

    const int N = in_sizes[0] / 32;    // 100000
    const int E = in_sizes[1] / 2;     // 1600000
    const int* src = ei;
    const int* dst = ei + E;

    // ws layout (64B-aligned chunks)
    char* p = (char*)d_ws;
    auto align64 = [](size_t v) { return (v + 63) & ~(size_t)63; };
    int* cnt_i      = (int*)p;                 p += align64((size_t)N * 4);
    int* row_start  = (int*)p;                 p += align64((size_t)(N + 1) * 4);
    int* cursor     = (int*)p;                 p += align64((size_t)N * 4);
    int* bsum       = (int*)p;                 p += align64((size_t)512 * 4);
    int* sorted_src = (int*)p;                 p += align64((size_t)E * 4);
    float* h        = (float*)p;               p += align64((size_t)N * 64 * 4);
    float* hW       = (float*)p;               p += align64((size_t)N * 32 * 4);

    const int NP = N + 1;                          // scan domain (virtual cnt[N]=0)
    const int NB = (NP + SCAN_CHUNK - 1) / SCAN_CHUNK;   // 98 <= 256

    hipMemsetAsync(cnt_i, 0, (size_t)N * 4, stream);

    hist_kernel<<<(E + 255) / 256, 256, 0, stream>>>(dst, cnt_i, E);
    scan1_kernel<<<NB, SCAN_BLK, 0, stream>>>(cnt_i, bsum, N);
    scan2_kernel<<<1, SCAN_BLK, 0, stream>>>(bsum, NB);
    scan3_kernel<<<NB, SCAN_BLK, 0, stream>>>(cnt_i, bsum, row_start, cursor, N);
    fill_kernel<<<(E + 255) / 256, 256, 0, stream>>>(src, dst, cursor, sorted_src, E);

    int nblk = (N + 3) / 4;   // one wave per node, 4 nodes per block
    layer1_kernel<<<nblk, 256, 0, stream>>>(x, row_start, sorted_src,
                                            W1l, b1, W1r, W2l, h, hW, N);
    layer2_kernel<<<nblk, 256, 0, stream>>>(h, hW, row_start, sorted_src,
                                            W2r, b2, out, N);
}

// Round 3
// 483.127 us; speedup vs baseline: 1.6676x; 1.1456x over previous
//
#include <hip/hip_runtime.h>
#include <hip/hip_bf16.h>

// GraphSAGE 2-layer forward, CSR-gather formulation (no float atomics).
// N=100000 nodes, E=1.6M edges, C: 32 -> 64 -> 32.
//
// Round-3 changes vs round 2:
//  - Gather loops batched: 8 wave-uniform index loads (scalar-load eligible)
//    then 4 independent 128B row-gathers per half-wave -> ILP instead of a
//    serial index->row latency chain per edge.
//  - layer1 LDS cut to 18.7KB (W2l read via L1) -> 8 blocks/CU -> 100% occ.

#define SCAN_BLK   256
#define SCAN_ITEMS 4
#define SCAN_CHUNK (SCAN_BLK * SCAN_ITEMS)   // 1024

__global__ void hist_kernel(const int* __restrict__ dst, int* __restrict__ cnt, int E) {
    int e = blockIdx.x * blockDim.x + threadIdx.x;
    if (e < E) atomicAdd(&cnt[dst[e]], 1);
}

__global__ void scan1_kernel(const int* __restrict__ cnt, int* __restrict__ bsum, int n) {
    __shared__ int red[SCAN_BLK];
    int base = blockIdx.x * SCAN_CHUNK + threadIdx.x * SCAN_ITEMS;
    int s = 0;
#pragma unroll
    for (int j = 0; j < SCAN_ITEMS; ++j) {
        int i = base + j;
        s += (i < n) ? cnt[i] : 0;
    }
    red[threadIdx.x] = s;
    __syncthreads();
    for (int off = SCAN_BLK / 2; off > 0; off >>= 1) {
        if (threadIdx.x < off) red[threadIdx.x] += red[threadIdx.x + off];
        __syncthreads();
    }
    if (threadIdx.x == 0) bsum[blockIdx.x] = red[0];
}

__global__ void scan2_kernel(int* __restrict__ bsum, int nb) {
    __shared__ int buf[SCAN_BLK];
    int t = threadIdx.x;
    int v = (t < nb) ? bsum[t] : 0;
    buf[t] = v;
    __syncthreads();
    for (int off = 1; off < SCAN_BLK; off <<= 1) {
        int add = (t >= off) ? buf[t - off] : 0;
        __syncthreads();
        buf[t] += add;
        __syncthreads();
    }
    if (t < nb) bsum[t] = buf[t] - v;   // exclusive
}

__global__ void scan3_kernel(const int* __restrict__ cnt, const int* __restrict__ bsum,
                             int* __restrict__ row_start, int* __restrict__ cursor, int n) {
    __shared__ int tsum[SCAN_BLK];
    int t = threadIdx.x;
    int base = blockIdx.x * SCAN_CHUNK + t * SCAN_ITEMS;
    int v[SCAN_ITEMS];
#pragma unroll
    for (int j = 0; j < SCAN_ITEMS; ++j) {
        int i = base + j;
        v[j] = (i < n) ? cnt[i] : 0;
    }
    int mine = v[0] + v[1] + v[2] + v[3];
    tsum[t] = mine;
    __syncthreads();
    for (int off = 1; off < SCAN_BLK; off <<= 1) {
        int add = (t >= off) ? tsum[t - off] : 0;
        __syncthreads();
        tsum[t] += add;
        __syncthreads();
    }
    int run = tsum[t] - mine + bsum[blockIdx.x];
#pragma unroll
    for (int j = 0; j < SCAN_ITEMS; ++j) {
        int i = base + j;
        if (i <= n) {
            row_start[i] = run;
            if (i < n) cursor[i] = run;
        }
        run += v[j];
    }
}

__global__ void fill_kernel(const int* __restrict__ src, const int* __restrict__ dst,
                            int* __restrict__ cursor, int* __restrict__ sorted_src, int E) {
    int e = blockIdx.x * blockDim.x + threadIdx.x;
    if (e < E) {
        int pos = atomicAdd(&cursor[dst[e]], 1);
        sorted_src[pos] = src[e];
    }
}

// Batched gather-sum of 32-ch rows for one node, one full wave.
// c = lane&31 (channel), half = lane>>5. Index loads are wave-uniform.
__device__ __forceinline__ float gather_rows32(const float* __restrict__ tbl,
                                               const int* __restrict__ sp,
                                               int deg, int c, int half) {
    float a0 = 0.0f, a1 = 0.0f;
    int j = 0;
    for (; j + 8 <= deg; j += 8) {
        int s0 = sp[j + 0], s1 = sp[j + 1], s2 = sp[j + 2], s3 = sp[j + 3];
        int s4 = sp[j + 4], s5 = sp[j + 5], s6 = sp[j + 6], s7 = sp[j + 7];
        int e0 = half ? s4 : s0;
        int e1 = half ? s5 : s1;
        int e2 = half ? s6 : s2;
        int e3 = half ? s7 : s3;
        a0 += tbl[(size_t)e0 * 32 + c];
        a1 += tbl[(size_t)e1 * 32 + c];
        a0 += tbl[(size_t)e2 * 32 + c];
        a1 += tbl[(size_t)e3 * 32 + c];
    }
    // tail (<8 edges): interleave halves
    for (int i = j + half; i < deg; i += 2)
        a0 += tbl[(size_t)sp[i] * 32 + c];
    float a = a0 + a1;
    a += __shfl_xor(a, 32);   // combine halves
    return a;
}

// one wave per node: agg = mean-gather x[src]; h = relu(agg@W1l + b1 + x@W1r);
// hW = h@W2l (pre-transform so layer-2 gathers 32ch instead of 64).
__global__ __launch_bounds__(256) void layer1_kernel(
        const float* __restrict__ x, const int* __restrict__ row_start,
        const int* __restrict__ sorted_src,
        const float* __restrict__ W1l, const float* __restrict__ b1,
        const float* __restrict__ W1r, const float* __restrict__ W2l,
        float* __restrict__ h, float* __restrict__ hW, int N) {
    __shared__ float sW1l[32 * 64];
    __shared__ float sW1r[32 * 64];
    __shared__ float sb1[64];
    __shared__ float sAgg[4][32];
    __shared__ float sX[4][32];
    __shared__ float sH[4][64];
    for (int i = threadIdx.x; i < 2048; i += 256) {
        sW1l[i] = W1l[i];
        sW1r[i] = W1r[i];
    }
    if (threadIdx.x < 64) sb1[threadIdx.x] = b1[threadIdx.x];
    __syncthreads();

    int w = threadIdx.x >> 6;
    int lane = threadIdx.x & 63;
    int n = blockIdx.x * 4 + w;
    bool active = n < N;
    int c = lane & 31, half = lane >> 5;

    float agg = 0.0f;
    float inv = 1.0f;
    if (active) {
        int rs = row_start[n];
        int re = row_start[n + 1];
        int deg = re - rs;
        inv = 1.0f / fmaxf((float)deg, 1.0f);
        agg = gather_rows32(x, sorted_src + rs, deg, c, half);
    }
    if (active && lane < 32) {
        sAgg[w][lane] = agg * inv;
        sX[w][lane] = x[(size_t)n * 32 + lane];
    }
    __syncthreads();

    float acc = sb1[lane];
    if (active) {
#pragma unroll
        for (int k = 0; k < 32; ++k)
            acc += sAgg[w][k] * sW1l[k * 64 + lane] + sX[w][k] * sW1r[k * 64 + lane];
    }
    float hv = fmaxf(acc, 0.0f);
    if (active) {
        h[(size_t)n * 64 + lane] = hv;
        sH[w][lane] = hv;
    }
    __syncthreads();

    if (active && lane < 32) {
        float a2 = 0.0f;
#pragma unroll
        for (int k = 0; k < 64; ++k) a2 += sH[w][k] * W2l[k * 32 + lane];
        hW[(size_t)n * 32 + lane] = a2;
    }
}

// one wave per node: out = mean-gather hW[src] + h@W2r + b2
__global__ __launch_bounds__(256) void layer2_kernel(
        const float* __restrict__ h, const float* __restrict__ hW,
        const int* __restrict__ row_start, const int* __restrict__ sorted_src,
        const float* __restrict__ W2r, const float* __restrict__ b2,
        float* __restrict__ out, int N) {
    __shared__ float sW2r[64 * 32];
    __shared__ float sb2[32];
    __shared__ float sH[4][64];
    for (int i = threadIdx.x; i < 2048; i += 256) sW2r[i] = W2r[i];
    if (threadIdx.x < 32) sb2[threadIdx.x] = b2[threadIdx.x];
    __syncthreads();

    int w = threadIdx.x >> 6;
    int lane = threadIdx.x & 63;
    int n = blockIdx.x * 4 + w;
    bool active = n < N;
    int c = lane & 31, half = lane >> 5;

    float a = 0.0f;
    float inv = 1.0f;
    if (active) {
        int rs = row_start[n];
        int re = row_start[n + 1];
        int deg = re - rs;
        inv = 1.0f / fmaxf((float)deg, 1.0f);
        a = gather_rows32(hW, sorted_src + rs, deg, c, half);
    }
    if (active) sH[w][lane] = h[(size_t)n * 64 + lane];
    __syncthreads();

    if (active) {
        float p = 0.0f;
#pragma unroll
        for (int kk = 0; kk < 32; ++kk) {
            int k = half * 32 + kk;
            p += sH[w][k] * sW2r[k * 32 + c];
        }
        p += __shfl_xor(p, 32);  // combine k-halves
        if (lane < 32) out[(size_t)n * 32 + c] = a * inv + sb2[c] + p;
    }
}

extern "C" void kernel_launch(void* const* d_in, const int* in_sizes, int n_in,
                              void* d_out, int out_size, void* d_ws, size_t ws_size,
                              hipStream_t stream) {
    const float* x   = (const float*)d_in[0];
    const int*   ei  = (const int*)d_in[1];
    const float* W1l = (const float*)d_in[2];
    const float* b1  = (const float*)d_in[3];
    const float* W1r = (const float*)d_in[4];
    const float* W2l = (const float*)d_in[5];
    const float* b2  = (const float*)d_in[6];
    const float* W2r = (const float*)d_in[7];
    float* out = (float*)d_out;

    const int N = in_sizes[0] / 32;    // 100000
    const int E = in_sizes[1] / 2;     // 1600000
    const int* src = ei;
    const int* dst = ei + E;

    char* p = (char*)d_ws;
    auto align64 = [](size_t v) { return (v + 63) & ~(size_t)63; };
    int* cnt_i      = (int*)p;                 p += align64((size_t)N * 4);
    int* row_start  = (int*)p;                 p += align64((size_t)(N + 1) * 4);
    int* cursor     = (int*)p;                 p += align64((size_t)N * 4);
    int* bsum       = (int*)p;                 p += align64((size_t)512 * 4);
    int* sorted_src = (int*)p;                 p += align64((size_t)E * 4);
    float* h        = (float*)p;               p += align64((size_t)N * 64 * 4);
    float* hW       = (float*)p;               p += align64((size_t)N * 32 * 4);

    const int NP = N + 1;
    const int NB = (NP + SCAN_CHUNK - 1) / SCAN_CHUNK;   // 98 <= 256

    hipMemsetAsync(cnt_i, 0, (size_t)N * 4, stream);

    hist_kernel<<<(E + 255) / 256, 256, 0, stream>>>(dst, cnt_i, E);
    scan1_kernel<<<NB, SCAN_BLK, 0, stream>>>(cnt_i, bsum, N);
    scan2_kernel<<<1, SCAN_BLK, 0, stream>>>(bsum, NB);
    scan3_kernel<<<NB, SCAN_BLK, 0, stream>>>(cnt_i, bsum, row_start, cursor, N);
    fill_kernel<<<(E + 255) / 256, 256, 0, stream>>>(src, dst, cursor, sorted_src, E);

    int nblk = (N + 3) / 4;
    layer1_kernel<<<nblk, 256, 0, stream>>>(x, row_start, sorted_src,
                                            W1l, b1, W1r, W2l, h, hW, N);
    layer2_kernel<<<nblk, 256, 0, stream>>>(h, hW, row_start, sorted_src,
                                            W2r, b2, out, N);
}

// Round 4
// 427.516 us; speedup vs baseline: 1.8845x; 1.1301x over previous
//
#include <hip/hip_runtime.h>
#include <hip/hip_bf16.h>

// GraphSAGE 2-layer forward, CSR-gather formulation.
// N=100000, E=1.6M, C: 32 -> 64 -> 32.
//
// Round-4:
//  - float4 gathers (8 lanes/row, 1 dwordx4 = 8 rows/wave) in both layers.
//  - layer1 fuses dense1 + hW(=h@W2l) + d2(=h@W2r+b2); h never hits memory.
//  - layer2 = gather-mean(hW) + d2 : no weights, no LDS.
//  - 512-thread layer1 blocks; single __syncthreads (weights only); all
//    node-phase LDS exchange is wave-internal (no imbalance coupling).

#define SCAN_BLK   256
#define SCAN_ITEMS 4
#define SCAN_CHUNK (SCAN_BLK * SCAN_ITEMS)   // 1024

__global__ void hist_kernel(const int* __restrict__ dst, int* __restrict__ cnt, int E) {
    int t = blockIdx.x * blockDim.x + threadIdx.x;
    int e = t * 4;
    if (e + 4 <= E) {
        int4 d = *reinterpret_cast<const int4*>(dst + e);
        atomicAdd(&cnt[d.x], 1);
        atomicAdd(&cnt[d.y], 1);
        atomicAdd(&cnt[d.z], 1);
        atomicAdd(&cnt[d.w], 1);
    } else {
        for (int i = e; i < E; ++i) atomicAdd(&cnt[dst[i]], 1);
    }
}

__global__ void scan1_kernel(const int* __restrict__ cnt, int* __restrict__ bsum, int n) {
    __shared__ int red[SCAN_BLK];
    int base = blockIdx.x * SCAN_CHUNK + threadIdx.x * SCAN_ITEMS;
    int s = 0;
#pragma unroll
    for (int j = 0; j < SCAN_ITEMS; ++j) {
        int i = base + j;
        s += (i < n) ? cnt[i] : 0;
    }
    red[threadIdx.x] = s;
    __syncthreads();
    for (int off = SCAN_BLK / 2; off > 0; off >>= 1) {
        if (threadIdx.x < off) red[threadIdx.x] += red[threadIdx.x + off];
        __syncthreads();
    }
    if (threadIdx.x == 0) bsum[blockIdx.x] = red[0];
}

__global__ void scan2_kernel(int* __restrict__ bsum, int nb) {
    __shared__ int buf[SCAN_BLK];
    int t = threadIdx.x;
    int v = (t < nb) ? bsum[t] : 0;
    buf[t] = v;
    __syncthreads();
    for (int off = 1; off < SCAN_BLK; off <<= 1) {
        int add = (t >= off) ? buf[t - off] : 0;
        __syncthreads();
        buf[t] += add;
        __syncthreads();
    }
    if (t < nb) bsum[t] = buf[t] - v;   // exclusive
}

__global__ void scan3_kernel(const int* __restrict__ cnt, const int* __restrict__ bsum,
                             int* __restrict__ row_start, int* __restrict__ cursor, int n) {
    __shared__ int tsum[SCAN_BLK];
    int t = threadIdx.x;
    int base = blockIdx.x * SCAN_CHUNK + t * SCAN_ITEMS;
    int v[SCAN_ITEMS];
#pragma unroll
    for (int j = 0; j < SCAN_ITEMS; ++j) {
        int i = base + j;
        v[j] = (i < n) ? cnt[i] : 0;
    }
    int mine = v[0] + v[1] + v[2] + v[3];
    tsum[t] = mine;
    __syncthreads();
    for (int off = 1; off < SCAN_BLK; off <<= 1) {
        int add = (t >= off) ? tsum[t - off] : 0;
        __syncthreads();
        tsum[t] += add;
        __syncthreads();
    }
    int run = tsum[t] - mine + bsum[blockIdx.x];
#pragma unroll
    for (int j = 0; j < SCAN_ITEMS; ++j) {
        int i = base + j;
        if (i <= n) {
            row_start[i] = run;
            if (i < n) cursor[i] = run;
        }
        run += v[j];
    }
}

__global__ void fill_kernel(const int* __restrict__ src, const int* __restrict__ dst,
                            int* __restrict__ cursor, int* __restrict__ sorted_src, int E) {
    int t = blockIdx.x * blockDim.x + threadIdx.x;
    int e = t * 4;
    if (e + 4 <= E) {
        int4 s = *reinterpret_cast<const int4*>(src + e);
        int4 d = *reinterpret_cast<const int4*>(dst + e);
        int p0 = atomicAdd(&cursor[d.x], 1); sorted_src[p0] = s.x;
        int p1 = atomicAdd(&cursor[d.y], 1); sorted_src[p1] = s.y;
        int p2 = atomicAdd(&cursor[d.z], 1); sorted_src[p2] = s.z;
        int p3 = atomicAdd(&cursor[d.w], 1); sorted_src[p3] = s.w;
    } else {
        for (int i = e; i < E; ++i) {
            int p = atomicAdd(&cursor[dst[i]], 1);
            sorted_src[p] = src[i];
        }
    }
}

// ---- layer1 (fused): one wave per node, 8 nodes / 512-thread block ----
// gather-mean x[src] (float4, 8 lanes/row) -> h = relu(agg@W1l + b1 + x@W1r)
// -> hW = h@W2l, d2 = h@W2r + b2   (h stays in LDS/registers)
__global__ __launch_bounds__(512) void layer1_kernel(
        const float* __restrict__ x, const int* __restrict__ row_start,
        const int* __restrict__ sorted_src,
        const float* __restrict__ W1l, const float* __restrict__ b1,
        const float* __restrict__ W1r, const float* __restrict__ W2l,
        const float* __restrict__ W2r, const float* __restrict__ b2,
        float* __restrict__ hW, float* __restrict__ d2, int N) {
    __shared__ float sW1l[32 * 64];   // [k][oc]
    __shared__ float sW1r[32 * 64];
    __shared__ float sW2l[64 * 32];
    __shared__ float sW2r[64 * 32];
    __shared__ float sb1[64], sb2[32];
    __shared__ float sAgg[8][32], sX[8][32], sH[8][64];

    {
        int t = threadIdx.x;          // 0..511 ; each matrix = 512 float4
        ((float4*)sW1l)[t] = ((const float4*)W1l)[t];
        ((float4*)sW1r)[t] = ((const float4*)W1r)[t];
        ((float4*)sW2l)[t] = ((const float4*)W2l)[t];
        ((float4*)sW2r)[t] = ((const float4*)W2r)[t];
        if (t < 64) sb1[t] = b1[t];
        if (t < 32) sb2[t] = b2[t];
    }
    __syncthreads();                  // the only block-wide barrier

    const int w = threadIdx.x >> 6;
    const int lane = threadIdx.x & 63;
    const int n = blockIdx.x * 8 + w;
    if (n >= N) return;               // whole wave exits; no barrier below

    const int sub = lane & 7;         // channel quarter (4 floats)
    const int rowi = lane >> 3;       // row within batch of 8

    int rs = row_start[n];
    int re = row_start[n + 1];
    int deg = re - rs;
    float inv = 1.0f / fmaxf((float)deg, 1.0f);
    const int* sp = sorted_src + rs;
    const float4* x4 = (const float4*)x;

    float4 acc = make_float4(0.f, 0.f, 0.f, 0.f);
    int j = 0;
    for (; j + 8 <= deg; j += 8) {
        int e = sp[j + rowi];
        float4 v = x4[(size_t)e * 8 + sub];
        acc.x += v.x; acc.y += v.y; acc.z += v.z; acc.w += v.w;
    }
    int rem = deg - j;
    if (rowi < rem) {
        int e = sp[j + rowi];
        float4 v = x4[(size_t)e * 8 + sub];
        acc.x += v.x; acc.y += v.y; acc.z += v.z; acc.w += v.w;
    }
#pragma unroll
    for (int off = 8; off < 64; off <<= 1) {   // reduce over the 8 row-groups
        acc.x += __shfl_xor(acc.x, off);
        acc.y += __shfl_xor(acc.y, off);
        acc.z += __shfl_xor(acc.z, off);
        acc.w += __shfl_xor(acc.w, off);
    }
    if (lane < 8) {
        float4 m;
        m.x = acc.x * inv; m.y = acc.y * inv; m.z = acc.z * inv; m.w = acc.w * inv;
        ((float4*)sAgg[w])[lane] = m;
        ((float4*)sX[w])[lane] = x4[(size_t)n * 8 + lane];
    }
    // wave-internal LDS exchange: lockstep wave, compiler inserts lgkmcnt

    float accd = sb1[lane];
#pragma unroll
    for (int k = 0; k < 32; ++k)
        accd += sAgg[w][k] * sW1l[k * 64 + lane] + sX[w][k] * sW1r[k * 64 + lane];
    float hv = fmaxf(accd, 0.0f);
    sH[w][lane] = hv;

    const int c2 = lane & 31;
    const int half = lane >> 5;
    float p1 = 0.f, p2 = 0.f;
#pragma unroll
    for (int kk = 0; kk < 32; ++kk) {
        int k = half * 32 + kk;
        float hk = sH[w][k];
        p1 += hk * sW2l[k * 32 + c2];
        p2 += hk * sW2r[k * 32 + c2];
    }
    p1 += __shfl_xor(p1, 32);         // combine k-halves
    p2 += __shfl_xor(p2, 32);
    if (lane < 32) {
        hW[(size_t)n * 32 + c2] = p1;
        d2[(size_t)n * 32 + c2] = p2 + sb2[c2];
    }
}

// ---- layer2: out = gather-mean(hW[src]) + d2 ----
__global__ __launch_bounds__(256) void layer2_kernel(
        const float* __restrict__ hW, const float* __restrict__ d2,
        const int* __restrict__ row_start, const int* __restrict__ sorted_src,
        float* __restrict__ out, int N) {
    const int w = threadIdx.x >> 6;
    const int lane = threadIdx.x & 63;
    const int n = blockIdx.x * 4 + w;
    if (n >= N) return;

    const int sub = lane & 7;
    const int rowi = lane >> 3;
    int rs = row_start[n];
    int re = row_start[n + 1];
    int deg = re - rs;
    float inv = 1.0f / fmaxf((float)deg, 1.0f);
    const int* sp = sorted_src + rs;
    const float4* t4 = (const float4*)hW;

    float4 acc = make_float4(0.f, 0.f, 0.f, 0.f);
    int j = 0;
    for (; j + 8 <= deg; j += 8) {
        int e = sp[j + rowi];
        float4 v = t4[(size_t)e * 8 + sub];
        acc.x += v.x; acc.y += v.y; acc.z += v.z; acc.w += v.w;
    }
    int rem = deg - j;
    if (rowi < rem) {
        int e = sp[j + rowi];
        float4 v = t4[(size_t)e * 8 + sub];
        acc.x += v.x; acc.y += v.y; acc.z += v.z; acc.w += v.w;
    }
#pragma unroll
    for (int off = 8; off < 64; off <<= 1) {
        acc.x += __shfl_xor(acc.x, off);
        acc.y += __shfl_xor(acc.y, off);
        acc.z += __shfl_xor(acc.z, off);
        acc.w += __shfl_xor(acc.w, off);
    }
    if (lane < 8) {
        float4 dd = ((const float4*)d2)[(size_t)n * 8 + lane];
        float4 o;
        o.x = acc.x * inv + dd.x;
        o.y = acc.y * inv + dd.y;
        o.z = acc.z * inv + dd.z;
        o.w = acc.w * inv + dd.w;
        ((float4*)out)[(size_t)n * 8 + lane] = o;
    }
}

extern "C" void kernel_launch(void* const* d_in, const int* in_sizes, int n_in,
                              void* d_out, int out_size, void* d_ws, size_t ws_size,
                              hipStream_t stream) {
    const float* x   = (const float*)d_in[0];
    const int*   ei  = (const int*)d_in[1];
    const float* W1l = (const float*)d_in[2];
    const float* b1  = (const float*)d_in[3];
    const float* W1r = (const float*)d_in[4];
    const float* W2l = (const float*)d_in[5];
    const float* b2  = (const float*)d_in[6];
    const float* W2r = (const float*)d_in[7];
    float* out = (float*)d_out;

    const int N = in_sizes[0] / 32;    // 100000
    const int E = in_sizes[1] / 2;     // 1600000
    const int* src = ei;
    const int* dst = ei + E;

    char* p = (char*)d_ws;
    auto align64 = [](size_t v) { return (v + 63) & ~(size_t)63; };
    int* cnt_i      = (int*)p;                 p += align64((size_t)N * 4);
    int* row_start  = (int*)p;                 p += align64((size_t)(N + 1) * 4);
    int* cursor     = (int*)p;                 p += align64((size_t)N * 4);
    int* bsum       = (int*)p;                 p += align64((size_t)512 * 4);
    int* sorted_src = (int*)p;                 p += align64((size_t)E * 4);
    float* hW       = (float*)p;               p += align64((size_t)N * 32 * 4);
    float* d2       = (float*)p;               p += align64((size_t)N * 32 * 4);

    const int NP = N + 1;
    const int NB = (NP + SCAN_CHUNK - 1) / SCAN_CHUNK;   // 98 <= 256

    hipMemsetAsync(cnt_i, 0, (size_t)N * 4, stream);

    int eblk = ((E + 3) / 4 + 255) / 256;
    hist_kernel<<<eblk, 256, 0, stream>>>(dst, cnt_i, E);
    scan1_kernel<<<NB, SCAN_BLK, 0, stream>>>(cnt_i, bsum, N);
    scan2_kernel<<<1, SCAN_BLK, 0, stream>>>(bsum, NB);
    scan3_kernel<<<NB, SCAN_BLK, 0, stream>>>(cnt_i, bsum, row_start, cursor, N);
    fill_kernel<<<eblk, 256, 0, stream>>>(src, dst, cursor, sorted_src, E);

    layer1_kernel<<<(N + 7) / 8, 512, 0, stream>>>(x, row_start, sorted_src,
                                                   W1l, b1, W1r, W2l, W2r, b2,
                                                   hW, d2, N);
    layer2_kernel<<<(N + 3) / 4, 256, 0, stream>>>(hW, d2, row_start, sorted_src,
                                                   out, N);
}

// Round 5
// 278.162 us; speedup vs baseline: 2.8964x; 1.5369x over previous
//
#include <hip/hip_runtime.h>
#include <hip/hip_bf16.h>

// GraphSAGE 2-layer forward. N=100000, E=1.6M, C: 32 -> 64 -> 32.
//
// Round-5: replace hist/scan/fill CSR build (108MB of write-amplified HBM
// traffic, 190us) with a bucket counting-sort:
//   partition:  tile-local LDS ranking -> packed (ldst<<24|src) into
//               per-bucket fixed-cap regions (time-local writes, ~1x ampl.)
//   bucket_scan: 391 bucket sizes -> exclusive scan (1 block)
//   bucket_csr: per-bucket CSR build entirely in LDS; row_start/sorted_src
//               written as coalesced streams.
// Layers unchanged from round 4 (fused dense, float4 gathers).

#define BUCKET_SHIFT 8
#define BUCKET_SPAN  256            // nodes per bucket
#define BUCKET_CAP   8192           // mean 4092, +64 sigma headroom
#define PART_ITEMS   32             // edges per thread per tile
#define PART_TILE    (256 * PART_ITEMS)   // 8192 edges

// ---- partition: scatter edges into bucket regions, packed ----
__global__ __launch_bounds__(256) void partition_kernel(
        const int* __restrict__ src, const int* __restrict__ dst,
        int* __restrict__ cursorB, int* __restrict__ edgesB, int E, int nbuck) {
    __shared__ int hist[512];
    __shared__ int rank_[512];
    __shared__ int base[512];
    const int tid = threadIdx.x;
    const int tbase = blockIdx.x * PART_TILE;

    for (int i = tid; i < 512; i += 256) { hist[i] = 0; rank_[i] = 0; }
    __syncthreads();

#pragma unroll
    for (int it = 0; it < PART_ITEMS; ++it) {
        int idx = tbase + it * 256 + tid;
        if (idx < E) atomicAdd(&hist[dst[idx] >> BUCKET_SHIFT], 1);
    }
    __syncthreads();

    for (int i = tid; i < nbuck; i += 256) {
        int h = hist[i];
        base[i] = h ? atomicAdd(&cursorB[i], h) : 0;
    }
    __syncthreads();

#pragma unroll
    for (int it = 0; it < PART_ITEMS; ++it) {
        int idx = tbase + it * 256 + tid;
        if (idx < E) {
            int d = dst[idx];
            int b = d >> BUCKET_SHIFT;
            int ld = d & (BUCKET_SPAN - 1);
            int r = atomicAdd(&rank_[b], 1);
            edgesB[(size_t)b * BUCKET_CAP + base[b] + r] = (ld << 24) | src[idx];
        }
    }
}

// ---- exclusive scan of bucket sizes (single block) ----
__global__ __launch_bounds__(512) void bucket_scan_kernel(
        const int* __restrict__ cursorB, int* __restrict__ bucketStart, int nbuck) {
    __shared__ int s[512];
    int t = threadIdx.x;
    int v = (t < nbuck) ? cursorB[t] : 0;
    s[t] = v;
    __syncthreads();
    for (int off = 1; off < 512; off <<= 1) {
        int a = (t >= off) ? s[t - off] : 0;
        __syncthreads();
        s[t] += a;
        __syncthreads();
    }
    if (t < nbuck) bucketStart[t] = s[t] - v;
}

// ---- per-bucket CSR build, all staging in LDS ----
__global__ __launch_bounds__(256) void bucket_csr_kernel(
        const int* __restrict__ cursorB, const int* __restrict__ bucketStart,
        const int* __restrict__ edgesB, int* __restrict__ row_start,
        int* __restrict__ sorted_src, int N, int nbuck) {
    __shared__ int cnt[BUCKET_SPAN];
    __shared__ int cur[BUCKET_SPAN];
    __shared__ int sc[BUCKET_SPAN];
    __shared__ int sorted[BUCKET_CAP];

    const int b = blockIdx.x;
    const int t = threadIdx.x;
    const int nodeBase = b << BUCKET_SHIFT;
    const int span = min(BUCKET_SPAN, N - nodeBase);
    const int size = cursorB[b];
    const int gstart = bucketStart[b];
    const int* eb = edgesB + (size_t)b * BUCKET_CAP;

    cnt[t] = 0;
    __syncthreads();
    for (int i = t; i < size; i += 256) atomicAdd(&cnt[((unsigned)eb[i]) >> 24], 1);
    __syncthreads();

    sc[t] = cnt[t];
    __syncthreads();
    for (int off = 1; off < BUCKET_SPAN; off <<= 1) {
        int a = (t >= off) ? sc[t - off] : 0;
        __syncthreads();
        sc[t] += a;
        __syncthreads();
    }
    int excl = sc[t] - cnt[t];
    if (t < span) row_start[nodeBase + t] = gstart + excl;
    if (b == nbuck - 1 && t == 0) row_start[N] = gstart + size;
    cur[t] = excl;
    __syncthreads();

    for (int i = t; i < size; i += 256) {
        int p = eb[i];
        int r = atomicAdd(&cur[((unsigned)p) >> 24], 1);
        sorted[r] = p & 0xFFFFFF;
    }
    __syncthreads();
    for (int i = t; i < size; i += 256) sorted_src[gstart + i] = sorted[i];
}

// ---- layer1 (fused): one wave per node, 8 nodes / 512-thread block ----
__global__ __launch_bounds__(512) void layer1_kernel(
        const float* __restrict__ x, const int* __restrict__ row_start,
        const int* __restrict__ sorted_src,
        const float* __restrict__ W1l, const float* __restrict__ b1,
        const float* __restrict__ W1r, const float* __restrict__ W2l,
        const float* __restrict__ W2r, const float* __restrict__ b2,
        float* __restrict__ hW, float* __restrict__ d2, int N) {
    __shared__ float sW1l[32 * 64];
    __shared__ float sW1r[32 * 64];
    __shared__ float sW2l[64 * 32];
    __shared__ float sW2r[64 * 32];
    __shared__ float sb1[64], sb2[32];
    __shared__ float sAgg[8][32], sX[8][32], sH[8][64];

    {
        int t = threadIdx.x;
        ((float4*)sW1l)[t] = ((const float4*)W1l)[t];
        ((float4*)sW1r)[t] = ((const float4*)W1r)[t];
        ((float4*)sW2l)[t] = ((const float4*)W2l)[t];
        ((float4*)sW2r)[t] = ((const float4*)W2r)[t];
        if (t < 64) sb1[t] = b1[t];
        if (t < 32) sb2[t] = b2[t];
    }
    __syncthreads();

    const int w = threadIdx.x >> 6;
    const int lane = threadIdx.x & 63;
    const int n = blockIdx.x * 8 + w;
    if (n >= N) return;

    const int sub = lane & 7;
    const int rowi = lane >> 3;

    int rs = row_start[n];
    int re = row_start[n + 1];
    int deg = re - rs;
    float inv = 1.0f / fmaxf((float)deg, 1.0f);
    const int* sp = sorted_src + rs;
    const float4* x4 = (const float4*)x;

    float4 acc = make_float4(0.f, 0.f, 0.f, 0.f);
    int j = 0;
    for (; j + 8 <= deg; j += 8) {
        int e = sp[j + rowi];
        float4 v = x4[(size_t)e * 8 + sub];
        acc.x += v.x; acc.y += v.y; acc.z += v.z; acc.w += v.w;
    }
    int rem = deg - j;
    if (rowi < rem) {
        int e = sp[j + rowi];
        float4 v = x4[(size_t)e * 8 + sub];
        acc.x += v.x; acc.y += v.y; acc.z += v.z; acc.w += v.w;
    }
#pragma unroll
    for (int off = 8; off < 64; off <<= 1) {
        acc.x += __shfl_xor(acc.x, off);
        acc.y += __shfl_xor(acc.y, off);
        acc.z += __shfl_xor(acc.z, off);
        acc.w += __shfl_xor(acc.w, off);
    }
    if (lane < 8) {
        float4 m;
        m.x = acc.x * inv; m.y = acc.y * inv; m.z = acc.z * inv; m.w = acc.w * inv;
        ((float4*)sAgg[w])[lane] = m;
        ((float4*)sX[w])[lane] = x4[(size_t)n * 8 + lane];
    }
    // wave-internal LDS exchange (lockstep wave; compiler inserts lgkmcnt)

    float accd = sb1[lane];
#pragma unroll
    for (int k = 0; k < 32; ++k)
        accd += sAgg[w][k] * sW1l[k * 64 + lane] + sX[w][k] * sW1r[k * 64 + lane];
    float hv = fmaxf(accd, 0.0f);
    sH[w][lane] = hv;

    const int c2 = lane & 31;
    const int half = lane >> 5;
    float p1 = 0.f, p2 = 0.f;
#pragma unroll
    for (int kk = 0; kk < 32; ++kk) {
        int k = half * 32 + kk;
        float hk = sH[w][k];
        p1 += hk * sW2l[k * 32 + c2];
        p2 += hk * sW2r[k * 32 + c2];
    }
    p1 += __shfl_xor(p1, 32);
    p2 += __shfl_xor(p2, 32);
    if (lane < 32) {
        hW[(size_t)n * 32 + c2] = p1;
        d2[(size_t)n * 32 + c2] = p2 + sb2[c2];
    }
}

// ---- layer2: out = gather-mean(hW[src]) + d2 ----
__global__ __launch_bounds__(256) void layer2_kernel(
        const float* __restrict__ hW, const float* __restrict__ d2,
        const int* __restrict__ row_start, const int* __restrict__ sorted_src,
        float* __restrict__ out, int N) {
    const int w = threadIdx.x >> 6;
    const int lane = threadIdx.x & 63;
    const int n = blockIdx.x * 4 + w;
    if (n >= N) return;

    const int sub = lane & 7;
    const int rowi = lane >> 3;
    int rs = row_start[n];
    int re = row_start[n + 1];
    int deg = re - rs;
    float inv = 1.0f / fmaxf((float)deg, 1.0f);
    const int* sp = sorted_src + rs;
    const float4* t4 = (const float4*)hW;

    float4 acc = make_float4(0.f, 0.f, 0.f, 0.f);
    int j = 0;
    for (; j + 8 <= deg; j += 8) {
        int e = sp[j + rowi];
        float4 v = t4[(size_t)e * 8 + sub];
        acc.x += v.x; acc.y += v.y; acc.z += v.z; acc.w += v.w;
    }
    int rem = deg - j;
    if (rowi < rem) {
        int e = sp[j + rowi];
        float4 v = t4[(size_t)e * 8 + sub];
        acc.x += v.x; acc.y += v.y; acc.z += v.z; acc.w += v.w;
    }
#pragma unroll
    for (int off = 8; off < 64; off <<= 1) {
        acc.x += __shfl_xor(acc.x, off);
        acc.y += __shfl_xor(acc.y, off);
        acc.z += __shfl_xor(acc.z, off);
        acc.w += __shfl_xor(acc.w, off);
    }
    if (lane < 8) {
        float4 dd = ((const float4*)d2)[(size_t)n * 8 + lane];
        float4 o;
        o.x = acc.x * inv + dd.x;
        o.y = acc.y * inv + dd.y;
        o.z = acc.z * inv + dd.z;
        o.w = acc.w * inv + dd.w;
        ((float4*)out)[(size_t)n * 8 + lane] = o;
    }
}

extern "C" void kernel_launch(void* const* d_in, const int* in_sizes, int n_in,
                              void* d_out, int out_size, void* d_ws, size_t ws_size,
                              hipStream_t stream) {
    const float* x   = (const float*)d_in[0];
    const int*   ei  = (const int*)d_in[1];
    const float* W1l = (const float*)d_in[2];
    const float* b1  = (const float*)d_in[3];
    const float* W1r = (const float*)d_in[4];
    const float* W2l = (const float*)d_in[5];
    const float* b2  = (const float*)d_in[6];
    const float* W2r = (const float*)d_in[7];
    float* out = (float*)d_out;

    const int N = in_sizes[0] / 32;    // 100000
    const int E = in_sizes[1] / 2;     // 1600000
    const int* src = ei;
    const int* dst = ei + E;
    const int NBUCK = (N + BUCKET_SPAN - 1) >> BUCKET_SHIFT;   // 391

    char* p = (char*)d_ws;
    auto align64 = [](size_t v) { return (v + 63) & ~(size_t)63; };
    int* cursorB     = (int*)p;   p += align64((size_t)NBUCK * 4);
    int* bucketStart = (int*)p;   p += align64((size_t)(NBUCK + 1) * 4);
    int* row_start   = (int*)p;   p += align64((size_t)(N + 1) * 4);
    int* sorted_src  = (int*)p;   p += align64((size_t)E * 4);
    int* edgesB      = (int*)p;   p += align64((size_t)NBUCK * BUCKET_CAP * 4);
    float* hW        = (float*)p; p += align64((size_t)N * 32 * 4);
    float* d2        = (float*)p; p += align64((size_t)N * 32 * 4);

    hipMemsetAsync(cursorB, 0, (size_t)NBUCK * 4, stream);

    int ntiles = (E + PART_TILE - 1) / PART_TILE;   // 196
    partition_kernel<<<ntiles, 256, 0, stream>>>(src, dst, cursorB, edgesB, E, NBUCK);
    bucket_scan_kernel<<<1, 512, 0, stream>>>(cursorB, bucketStart, NBUCK);
    bucket_csr_kernel<<<NBUCK, 256, 0, stream>>>(cursorB, bucketStart, edgesB,
                                                 row_start, sorted_src, N, NBUCK);

    layer1_kernel<<<(N + 7) / 8, 512, 0, stream>>>(x, row_start, sorted_src,
                                                   W1l, b1, W1r, W2l, W2r, b2,
                                                   hW, d2, N);
    layer2_kernel<<<(N + 3) / 4, 256, 0, stream>>>(hW, d2, row_start, sorted_src,
                                                   out, N);
}

// Round 6
// 263.315 us; speedup vs baseline: 3.0597x; 1.0564x over previous
//
#include <hip/hip_runtime.h>
#include <hip/hip_bf16.h>
#include <hip/hip_fp16.h>

// GraphSAGE 2-layer forward. N=100000, E=1.6M, C: 32 -> 64 -> 32.
//
// Round-6:
//  - gather restructure: one coalesced index load per node (<=64 edges),
//    __shfl broadcast, up to 8 row-gathers issued back-to-back into a
//    statically-unrolled register array (kills the idx->row latency chain).
//  - hW stored fp16: layer2 gather table 12.8MB -> 6.4MB (near L2-resident),
//    half the gather bytes.
// CSR bucket build unchanged from round 5.

#define BUCKET_SHIFT 8
#define BUCKET_SPAN  256
#define BUCKET_CAP   8192
#define PART_ITEMS   32
#define PART_TILE    (256 * PART_ITEMS)   // 8192 edges

// ---- partition: scatter edges into bucket regions, packed ----
__global__ __launch_bounds__(256) void partition_kernel(
        const int* __restrict__ src, const int* __restrict__ dst,
        int* __restrict__ cursorB, int* __restrict__ edgesB, int E, int nbuck) {
    __shared__ int hist[512];
    __shared__ int rank_[512];
    __shared__ int base[512];
    const int tid = threadIdx.x;
    const int tbase = blockIdx.x * PART_TILE;

    for (int i = tid; i < 512; i += 256) { hist[i] = 0; rank_[i] = 0; }
    __syncthreads();

#pragma unroll
    for (int it = 0; it < PART_ITEMS; ++it) {
        int idx = tbase + it * 256 + tid;
        if (idx < E) atomicAdd(&hist[dst[idx] >> BUCKET_SHIFT], 1);
    }
    __syncthreads();

    for (int i = tid; i < nbuck; i += 256) {
        int h = hist[i];
        base[i] = h ? atomicAdd(&cursorB[i], h) : 0;
    }
    __syncthreads();

#pragma unroll
    for (int it = 0; it < PART_ITEMS; ++it) {
        int idx = tbase + it * 256 + tid;
        if (idx < E) {
            int d = dst[idx];
            int b = d >> BUCKET_SHIFT;
            int ld = d & (BUCKET_SPAN - 1);
            int r = atomicAdd(&rank_[b], 1);
            edgesB[(size_t)b * BUCKET_CAP + base[b] + r] = (ld << 24) | src[idx];
        }
    }
}

__global__ __launch_bounds__(512) void bucket_scan_kernel(
        const int* __restrict__ cursorB, int* __restrict__ bucketStart, int nbuck) {
    __shared__ int s[512];
    int t = threadIdx.x;
    int v = (t < nbuck) ? cursorB[t] : 0;
    s[t] = v;
    __syncthreads();
    for (int off = 1; off < 512; off <<= 1) {
        int a = (t >= off) ? s[t - off] : 0;
        __syncthreads();
        s[t] += a;
        __syncthreads();
    }
    if (t < nbuck) bucketStart[t] = s[t] - v;
}

__global__ __launch_bounds__(256) void bucket_csr_kernel(
        const int* __restrict__ cursorB, const int* __restrict__ bucketStart,
        const int* __restrict__ edgesB, int* __restrict__ row_start,
        int* __restrict__ sorted_src, int N, int nbuck) {
    __shared__ int cnt[BUCKET_SPAN];
    __shared__ int cur[BUCKET_SPAN];
    __shared__ int sc[BUCKET_SPAN];
    __shared__ int sorted[BUCKET_CAP];

    const int b = blockIdx.x;
    const int t = threadIdx.x;
    const int nodeBase = b << BUCKET_SHIFT;
    const int span = min(BUCKET_SPAN, N - nodeBase);
    const int size = cursorB[b];
    const int gstart = bucketStart[b];
    const int* eb = edgesB + (size_t)b * BUCKET_CAP;

    cnt[t] = 0;
    __syncthreads();
    for (int i = t; i < size; i += 256) atomicAdd(&cnt[((unsigned)eb[i]) >> 24], 1);
    __syncthreads();

    sc[t] = cnt[t];
    __syncthreads();
    for (int off = 1; off < BUCKET_SPAN; off <<= 1) {
        int a = (t >= off) ? sc[t - off] : 0;
        __syncthreads();
        sc[t] += a;
        __syncthreads();
    }
    int excl = sc[t] - cnt[t];
    if (t < span) row_start[nodeBase + t] = gstart + excl;
    if (b == nbuck - 1 && t == 0) row_start[N] = gstart + size;
    cur[t] = excl;
    __syncthreads();

    for (int i = t; i < size; i += 256) {
        int p = eb[i];
        int r = atomicAdd(&cur[((unsigned)p) >> 24], 1);
        sorted[r] = p & 0xFFFFFF;
    }
    __syncthreads();
    for (int i = t; i < size; i += 256) sorted_src[gstart + i] = sorted[i];
}

// ---- wave-cooperative gather-sum, fp32 rows (32ch = 8 float4 units) ----
// One coalesced index load covers 64 edges; up to 8 row-gather instructions
// (8 rows each) issued back-to-back; indices broadcast via __shfl (no mem chain).
__device__ __forceinline__ float4 gather_sum_f32(const float4* __restrict__ t4,
                                                 const int* __restrict__ sp,
                                                 int deg, int lane) {
    const int sub = lane & 7;
    const int rowi = lane >> 3;
    float4 acc = make_float4(0.f, 0.f, 0.f, 0.f);
    for (int base = 0; base < deg; base += 64) {
        int chunk = min(deg - base, 64);
        int myidx = (lane < chunk) ? sp[base + lane] : -1;
        int nit = (chunk + 7) >> 3;
        int e[8];
        float4 v[8];
#pragma unroll
        for (int it = 0; it < 8; ++it)
            e[it] = (it < nit) ? __shfl(myidx, it * 8 + rowi) : -1;
#pragma unroll
        for (int it = 0; it < 8; ++it)
            v[it] = (e[it] >= 0) ? t4[(size_t)e[it] * 8 + sub]
                                 : make_float4(0.f, 0.f, 0.f, 0.f);
#pragma unroll
        for (int it = 0; it < 8; ++it) {
            acc.x += v[it].x; acc.y += v[it].y;
            acc.z += v[it].z; acc.w += v[it].w;
        }
    }
#pragma unroll
    for (int off = 8; off < 64; off <<= 1) {
        acc.x += __shfl_xor(acc.x, off);
        acc.y += __shfl_xor(acc.y, off);
        acc.z += __shfl_xor(acc.z, off);
        acc.w += __shfl_xor(acc.w, off);
    }
    return acc;
}

// ---- same, fp16 rows (32ch = 8 float2-sized units of 4 halves) ----
__device__ __forceinline__ float4 gather_sum_f16(const float2* __restrict__ t2,
                                                 const int* __restrict__ sp,
                                                 int deg, int lane) {
    const int sub = lane & 7;
    const int rowi = lane >> 3;
    float4 acc = make_float4(0.f, 0.f, 0.f, 0.f);
    for (int base = 0; base < deg; base += 64) {
        int chunk = min(deg - base, 64);
        int myidx = (lane < chunk) ? sp[base + lane] : -1;
        int nit = (chunk + 7) >> 3;
        int e[8];
        float2 v[8];
#pragma unroll
        for (int it = 0; it < 8; ++it)
            e[it] = (it < nit) ? __shfl(myidx, it * 8 + rowi) : -1;
#pragma unroll
        for (int it = 0; it < 8; ++it)
            v[it] = (e[it] >= 0) ? t2[(size_t)e[it] * 8 + sub]
                                 : make_float2(0.f, 0.f);
#pragma unroll
        for (int it = 0; it < 8; ++it) {
            const __half2* hp = (const __half2*)&v[it];
            float2 lo = __half22float2(hp[0]);
            float2 hi = __half22float2(hp[1]);
            acc.x += lo.x; acc.y += lo.y; acc.z += hi.x; acc.w += hi.y;
        }
    }
#pragma unroll
    for (int off = 8; off < 64; off <<= 1) {
        acc.x += __shfl_xor(acc.x, off);
        acc.y += __shfl_xor(acc.y, off);
        acc.z += __shfl_xor(acc.z, off);
        acc.w += __shfl_xor(acc.w, off);
    }
    return acc;
}

// ---- layer1 (fused): one wave per node, 8 nodes / 512-thread block ----
__global__ __launch_bounds__(512) void layer1_kernel(
        const float* __restrict__ x, const int* __restrict__ row_start,
        const int* __restrict__ sorted_src,
        const float* __restrict__ W1l, const float* __restrict__ b1,
        const float* __restrict__ W1r, const float* __restrict__ W2l,
        const float* __restrict__ W2r, const float* __restrict__ b2,
        __half* __restrict__ hWh, float* __restrict__ d2, int N) {
    __shared__ float sW1l[32 * 64];
    __shared__ float sW1r[32 * 64];
    __shared__ float sW2l[64 * 32];
    __shared__ float sW2r[64 * 32];
    __shared__ float sb1[64], sb2[32];
    __shared__ float sAgg[8][32], sX[8][32], sH[8][64];

    {
        int t = threadIdx.x;
        ((float4*)sW1l)[t] = ((const float4*)W1l)[t];
        ((float4*)sW1r)[t] = ((const float4*)W1r)[t];
        ((float4*)sW2l)[t] = ((const float4*)W2l)[t];
        ((float4*)sW2r)[t] = ((const float4*)W2r)[t];
        if (t < 64) sb1[t] = b1[t];
        if (t < 32) sb2[t] = b2[t];
    }
    __syncthreads();

    const int w = threadIdx.x >> 6;
    const int lane = threadIdx.x & 63;
    const int n = blockIdx.x * 8 + w;
    if (n >= N) return;

    int rs = row_start[n];
    int re = row_start[n + 1];
    int deg = re - rs;
    float inv = 1.0f / fmaxf((float)deg, 1.0f);
    const float4* x4 = (const float4*)x;

    float4 acc = gather_sum_f32(x4, sorted_src + rs, deg, lane);

    if (lane < 8) {
        float4 m;
        m.x = acc.x * inv; m.y = acc.y * inv; m.z = acc.z * inv; m.w = acc.w * inv;
        ((float4*)sAgg[w])[lane] = m;
        ((float4*)sX[w])[lane] = x4[(size_t)n * 8 + lane];
    }
    // wave-internal LDS exchange (lockstep wave; compiler inserts lgkmcnt)

    float accd = sb1[lane];
#pragma unroll
    for (int k = 0; k < 32; ++k)
        accd += sAgg[w][k] * sW1l[k * 64 + lane] + sX[w][k] * sW1r[k * 64 + lane];
    float hv = fmaxf(accd, 0.0f);
    sH[w][lane] = hv;

    const int c2 = lane & 31;
    const int half = lane >> 5;
    float p1 = 0.f, p2 = 0.f;
#pragma unroll
    for (int kk = 0; kk < 32; ++kk) {
        int k = half * 32 + kk;
        float hk = sH[w][k];
        p1 += hk * sW2l[k * 32 + c2];
        p2 += hk * sW2r[k * 32 + c2];
    }
    p1 += __shfl_xor(p1, 32);
    p2 += __shfl_xor(p2, 32);
    if (lane < 32) {
        hWh[(size_t)n * 32 + c2] = __float2half_rn(p1);
        d2[(size_t)n * 32 + c2] = p2 + sb2[c2];
    }
}

// ---- layer2: out = gather-mean(hW[src], fp16) + d2 ----
__global__ __launch_bounds__(256) void layer2_kernel(
        const __half* __restrict__ hWh, const float* __restrict__ d2,
        const int* __restrict__ row_start, const int* __restrict__ sorted_src,
        float* __restrict__ out, int N) {
    const int w = threadIdx.x >> 6;
    const int lane = threadIdx.x & 63;
    const int n = blockIdx.x * 4 + w;
    if (n >= N) return;

    int rs = row_start[n];
    int re = row_start[n + 1];
    int deg = re - rs;
    float inv = 1.0f / fmaxf((float)deg, 1.0f);

    float4 acc = gather_sum_f16((const float2*)hWh, sorted_src + rs, deg, lane);

    if (lane < 8) {
        float4 dd = ((const float4*)d2)[(size_t)n * 8 + lane];
        float4 o;
        o.x = acc.x * inv + dd.x;
        o.y = acc.y * inv + dd.y;
        o.z = acc.z * inv + dd.z;
        o.w = acc.w * inv + dd.w;
        ((float4*)out)[(size_t)n * 8 + lane] = o;
    }
}

extern "C" void kernel_launch(void* const* d_in, const int* in_sizes, int n_in,
                              void* d_out, int out_size, void* d_ws, size_t ws_size,
                              hipStream_t stream) {
    const float* x   = (const float*)d_in[0];
    const int*   ei  = (const int*)d_in[1];
    const float* W1l = (const float*)d_in[2];
    const float* b1  = (const float*)d_in[3];
    const float* W1r = (const float*)d_in[4];
    const float* W2l = (const float*)d_in[5];
    const float* b2  = (const float*)d_in[6];
    const float* W2r = (const float*)d_in[7];
    float* out = (float*)d_out;

    const int N = in_sizes[0] / 32;    // 100000
    const int E = in_sizes[1] / 2;     // 1600000
    const int* src = ei;
    const int* dst = ei + E;
    const int NBUCK = (N + BUCKET_SPAN - 1) >> BUCKET_SHIFT;   // 391

    char* p = (char*)d_ws;
    auto align64 = [](size_t v) { return (v + 63) & ~(size_t)63; };
    int* cursorB     = (int*)p;    p += align64((size_t)NBUCK * 4);
    int* bucketStart = (int*)p;    p += align64((size_t)(NBUCK + 1) * 4);
    int* row_start   = (int*)p;    p += align64((size_t)(N + 1) * 4);
    int* sorted_src  = (int*)p;    p += align64((size_t)E * 4);
    int* edgesB      = (int*)p;    p += align64((size_t)NBUCK * BUCKET_CAP * 4);
    __half* hWh      = (__half*)p; p += align64((size_t)N * 32 * 2);
    float* d2        = (float*)p;  p += align64((size_t)N * 32 * 4);

    hipMemsetAsync(cursorB, 0, (size_t)NBUCK * 4, stream);

    int ntiles = (E + PART_TILE - 1) / PART_TILE;   // 196
    partition_kernel<<<ntiles, 256, 0, stream>>>(src, dst, cursorB, edgesB, E, NBUCK);
    bucket_scan_kernel<<<1, 512, 0, stream>>>(cursorB, bucketStart, NBUCK);
    bucket_csr_kernel<<<NBUCK, 256, 0, stream>>>(cursorB, bucketStart, edgesB,
                                                 row_start, sorted_src, N, NBUCK);

    layer1_kernel<<<(N + 7) / 8, 512, 0, stream>>>(x, row_start, sorted_src,
                                                   W1l, b1, W1r, W2l, W2r, b2,
                                                   hWh, d2, N);
    layer2_kernel<<<(N + 3) / 4, 256, 0, stream>>>(hWh, d2, row_start, sorted_src,
                                                   out, N);
}